// Round 8
// baseline (417.334 us; speedup 1.0000x reference)
//
#include <hip/hip_runtime.h>

#define TT 256
#define BB 512
#define DD 128
#define HH 50
#define KK 5
#define AA 4
#define GSTRIDE 52

#define R50(X) X(0) X(1) X(2) X(3) X(4) X(5) X(6) X(7) X(8) X(9) \
  X(10) X(11) X(12) X(13) X(14) X(15) X(16) X(17) X(18) X(19) \
  X(20) X(21) X(22) X(23) X(24) X(25) X(26) X(27) X(28) X(29) \
  X(30) X(31) X(32) X(33) X(34) X(35) X(36) X(37) X(38) X(39) \
  X(40) X(41) X(42) X(43) X(44) X(45) X(46) X(47) X(48) X(49)

typedef _Float16 half4 __attribute__((ext_vector_type(4)));
typedef float f32x4 __attribute__((ext_vector_type(4)));

// ---------------- K0: weight prep ----------------
__global__ void k0_prep(const float* __restrict__ W_in,
                        const float* __restrict__ W_ctx,
                        const float* __restrict__ W_key,
                        const float* __restrict__ W_q,
                        const float* __restrict__ b_key,
                        const float* __restrict__ b_q,
                        float* __restrict__ WT, float* __restrict__ WHT,
                        float* __restrict__ WK2T, float* __restrict__ bias2) {
  int i = blockIdx.x * 256 + threadIdx.x;
  if (i < DD * 52) {
    int j = i / 52, h = i % 52;
    WT[i] = (h < HH) ? W_in[h * DD + j] : 0.f;
  }
  if (i < HH * 52) {
    int j = i / 52, h = i % 52;
    WHT[i] = (h < HH) ? W_ctx[h * (2 * HH) + HH + j] : 0.f;
  }
  if (i < HH * 64) {
    int j = i >> 6, l = i & 63;
    float v = 0.f;
    if (l < HH) v = W_ctx[l * (2 * HH) + j];
    else if (l < HH + KK) v = W_key[(l - HH) * HH + j];
    else if (l < HH + 2 * KK) v = W_q[(l - HH - KK) * HH + j];
    WK2T[i] = v;
  }
  if (i < 64) {
    float bv = 0.f;
    if (i >= HH && i < HH + KK) bv = b_key[i - HH];
    else if (i >= HH + KK && i < HH + 2 * KK) bv = b_q[i - HH - KK];
    bias2[i] = bv;
  }
}

// ---------------- K1 (fused): g = relu(x@W_in^T+b_in)@Wh^T + b_ctx --------
__global__ __launch_bounds__(256, 2) void k1_fused(
    const float* __restrict__ x, const float* __restrict__ WT,
    const float* __restrict__ WHT, const float* __restrict__ b_in,
    const float* __restrict__ b_ctx, float* __restrict__ g) {
  __shared__ float xs[256 * 17];
  const int tid = threadIdx.x;
  const float* __restrict__ xblk = x + (size_t)blockIdx.x * 256 * DD;

#define DECLA(h) float a##h = b_in[h];
  R50(DECLA)

#pragma unroll 1
  for (int jb = 0; jb < 8; ++jb) {
    __syncthreads();
#pragma unroll
    for (int u = 0; u < 4; ++u) {
      const int f = tid + u * 256;
      const int r = f >> 2, c4 = f & 3;
      const float4 v = *reinterpret_cast<const float4*>(
          xblk + (size_t)r * DD + jb * 16 + c4 * 4);
      float* d = &xs[r * 17 + c4 * 4];
      d[0] = v.x; d[1] = v.y; d[2] = v.z; d[3] = v.w;
    }
    __syncthreads();
    const float* __restrict__ xrow = &xs[tid * 17];
#pragma unroll
    for (int cc = 0; cc < 16; cc += 4) {
      const int j = jb * 16 + cc;
      const float xv0 = xrow[cc + 0];
      const float xv1 = xrow[cc + 1];
      const float xv2 = xrow[cc + 2];
      const float xv3 = xrow[cc + 3];
      const float* __restrict__ w0 = WT + (j + 0) * 52;
      const float* __restrict__ w1 = WT + (j + 1) * 52;
      const float* __restrict__ w2 = WT + (j + 2) * 52;
      const float* __restrict__ w3 = WT + (j + 3) * 52;
#define FMA4(h)                   \
  a##h = fmaf(xv0, w0[h], a##h);  \
  a##h = fmaf(xv1, w1[h], a##h);  \
  a##h = fmaf(xv2, w2[h], a##h);  \
  a##h = fmaf(xv3, w3[h], a##h);
      R50(FMA4)
    }
  }

#define RELUA(h) a##h = fmaxf(a##h, 0.f);
  R50(RELUA)

#define DECLG(h) float g##h = b_ctx[h];
  R50(DECLG)

#define GH(h) g##h = fmaf(av, wh[h], g##h);
#define GJ(j, an) { const float av = an; const float* __restrict__ wh = WHT + (j) * 52; R50(GH) }
  GJ(0, a0) GJ(1, a1) GJ(2, a2) GJ(3, a3) GJ(4, a4)
  GJ(5, a5) GJ(6, a6) GJ(7, a7) GJ(8, a8) GJ(9, a9)
  GJ(10, a10) GJ(11, a11) GJ(12, a12) GJ(13, a13) GJ(14, a14)
  GJ(15, a15) GJ(16, a16) GJ(17, a17) GJ(18, a18) GJ(19, a19)
  GJ(20, a20) GJ(21, a21) GJ(22, a22) GJ(23, a23) GJ(24, a24)
  GJ(25, a25) GJ(26, a26) GJ(27, a27) GJ(28, a28) GJ(29, a29)
  GJ(30, a30) GJ(31, a31) GJ(32, a32) GJ(33, a33) GJ(34, a34)
  GJ(35, a35) GJ(36, a36) GJ(37, a37) GJ(38, a38) GJ(39, a39)
  GJ(40, a40) GJ(41, a41) GJ(42, a42) GJ(43, a43) GJ(44, a44)
  GJ(45, a45) GJ(46, a46) GJ(47, a47) GJ(48, a48) GJ(49, a49)

  const int row = blockIdx.x * 256 + tid;
  float* __restrict__ gr = g + (size_t)row * GSTRIDE;
  *reinterpret_cast<float4*>(gr + 0) = make_float4(g0, g1, g2, g3);
  *reinterpret_cast<float4*>(gr + 4) = make_float4(g4, g5, g6, g7);
  *reinterpret_cast<float4*>(gr + 8) = make_float4(g8, g9, g10, g11);
  *reinterpret_cast<float4*>(gr + 12) = make_float4(g12, g13, g14, g15);
  *reinterpret_cast<float4*>(gr + 16) = make_float4(g16, g17, g18, g19);
  *reinterpret_cast<float4*>(gr + 20) = make_float4(g20, g21, g22, g23);
  *reinterpret_cast<float4*>(gr + 24) = make_float4(g24, g25, g26, g27);
  *reinterpret_cast<float4*>(gr + 28) = make_float4(g28, g29, g30, g31);
  *reinterpret_cast<float4*>(gr + 32) = make_float4(g32, g33, g34, g35);
  *reinterpret_cast<float4*>(gr + 36) = make_float4(g36, g37, g38, g39);
  *reinterpret_cast<float4*>(gr + 40) = make_float4(g40, g41, g42, g43);
  *reinterpret_cast<float4*>(gr + 44) = make_float4(g44, g45, g46, g47);
  *reinterpret_cast<float2*>(gr + 48) = make_float2(g48, g49);
}

// ---------------- K2: per-batch recurrence (512 blocks x 1 wave) -----------
__global__ __launch_bounds__(64, 1) void k2_rec(
    const float* __restrict__ g, const float* __restrict__ WK2T,
    const float* __restrict__ bias2, const float* __restrict__ first_context,
    float* __restrict__ ctxg, float* __restrict__ keyg,
    float* __restrict__ qg) {
  __shared__ __align__(16) float c_lds[64];
  const int b = blockIdx.x;
  const int lane = threadIdx.x;

#define WDECL(j)                            \
  float w##j = WK2T[(j) * 64 + lane];       \
  asm volatile("" : "+v"(w##j));
  R50(WDECL)
  const float bias = bias2[lane];

  const float c0v = (lane < HH) ? first_context[lane] : 0.f;
  c_lds[lane] = c0v;
  if (lane < HH) ctxg[((size_t)b * 257 + 0) * HH + lane] = c0v;

  float gvA = (lane < HH) ? g[((size_t)0 * BB + b) * GSTRIDE + lane] : 0.f;
  float gvB = (lane < HH) ? g[((size_t)1 * BB + b) * GSTRIDE + lane] : 0.f;
  float gvC = (lane < HH) ? g[((size_t)2 * BB + b) * GSTRIDE + lane] : 0.f;

#define DOTQ(j0, j1, j2, j3)                                            \
  {                                                                     \
    const float4 cv = *reinterpret_cast<const float4*>(&c_lds[j0]);     \
    acc0 = fmaf(w##j0, cv.x, acc0);                                     \
    acc1 = fmaf(w##j1, cv.y, acc1);                                     \
    acc2 = fmaf(w##j2, cv.z, acc2);                                     \
    acc3 = fmaf(w##j3, cv.w, acc3);                                     \
  }
#define DOT50L                                                          \
  float acc0 = 0.f, acc1 = 0.f, acc2 = 0.f, acc3 = 0.f;                 \
  DOTQ(0, 1, 2, 3) DOTQ(4, 5, 6, 7) DOTQ(8, 9, 10, 11)                  \
  DOTQ(12, 13, 14, 15) DOTQ(16, 17, 18, 19) DOTQ(20, 21, 22, 23)        \
  DOTQ(24, 25, 26, 27) DOTQ(28, 29, 30, 31) DOTQ(32, 33, 34, 35)        \
  DOTQ(36, 37, 38, 39) DOTQ(40, 41, 42, 43) DOTQ(44, 45, 46, 47)        \
  {                                                                     \
    const float2 cv2 = *reinterpret_cast<const float2*>(&c_lds[48]);    \
    acc0 = fmaf(w48, cv2.x, acc0);                                      \
    acc1 = fmaf(w49, cv2.y, acc1);                                      \
  }                                                                     \
  const float acc = (acc0 + acc1) + (acc2 + acc3);

#pragma unroll 1
  for (int t = 0; t < TT; ++t) {
    float gvn = 0.f;
    if (lane < HH && (t + 3) < TT)
      gvn = g[((size_t)(t + 3) * BB + b) * GSTRIDE + lane];

    DOT50L

    if (lane >= HH && lane < HH + KK)
      keyg[((size_t)b * KK + (lane - HH)) * 257 + t] = acc + bias;
    if (lane >= HH + KK && lane < HH + 2 * KK && t >= 1)
      qg[((size_t)b * KK + (lane - HH - KK)) * 256 + (t - 1)] = acc + bias;

    const float cn = fmaxf(acc + gvA, 0.f);
    gvA = gvB;
    gvB = gvC;
    gvC = gvn;
    if (lane < HH) ctxg[((size_t)b * 257 + (t + 1)) * HH + lane] = cn;
    c_lds[lane] = cn;
  }

  {
    DOT50L
    if (lane >= HH && lane < HH + KK)
      keyg[((size_t)b * KK + (lane - HH)) * 257 + TT] = acc + bias;
    if (lane >= HH + KK && lane < HH + 2 * KK)
      qg[((size_t)b * KK + (lane - HH - KK)) * 256 + (TT - 1)] = acc + bias;
  }
}

// ---------------- K3: MFMA flash attention ----------------
// Block = (b, 32-t chunk), heavy-first. Swapped QK^T (S^T = K·Q) so the C
// fragment (col=lane&15 -> t, row=4*(lane>>4)+reg -> s) IS the A fragment
// PV needs (row=lane&15 -> t, k=4*(lane>>4)+i -> s): mask+exp+cvt in-lane.
// Waves split s (wave w owns s = 64*tile + 16w + ...). No LDS staging; all
// operand loads mask-guarded so MFMA inputs stay finite. Partial O/su
// combined via ds_add_f32; 128-thread epilogue applies W_act.
__global__ __launch_bounds__(256, 4) void k3_attn(
    const float* __restrict__ ctxg, const float* __restrict__ keyg,
    const float* __restrict__ qg, const float* __restrict__ W_act,
    const float* __restrict__ b_act, float* __restrict__ out) {
  __shared__ float o_l[32 * 66];  // [t_local][h=0..63] = O, [64] = su

  const int tid = threadIdx.x;
  const int bid = blockIdx.x;
  const int chunk = 7 - (bid >> 9);  // heavy-first
  const int b = bid & 511;
  const int tbase = chunk * 32;
  const int wave = tid >> 6;
  const int lane = tid & 63;
  const int lrow = lane & 15;
  const int lgrp = lane >> 4;

  for (int i = tid; i < 32 * 66; i += 256) o_l[i] = 0.f;

  // Q B-fragments (B[k][t]: t = lrow, k = 4*lgrp + i), one per 16-t tile
  half4 qf0, qf1;
#pragma unroll
  for (int i = 0; i < 4; ++i) {
    const int k = 4 * lgrp + i;
    const float q0 =
        (k < KK) ? qg[((size_t)b * KK + k) * 256 + tbase + lrow] : 0.f;
    const float q1 =
        (k < KK) ? qg[((size_t)b * KK + k) * 256 + tbase + 16 + lrow] : 0.f;
    qf0[i] = (_Float16)q0;
    qf1[i] = (_Float16)q1;
  }

  const f32x4 zf = {0.f, 0.f, 0.f, 0.f};
  f32x4 acc[2][4];
#pragma unroll
  for (int tt = 0; tt < 2; ++tt)
#pragma unroll
    for (int ht = 0; ht < 4; ++ht) acc[tt][ht] = zf;
  float su0 = 0.f, su1 = 0.f;

  const int tmax1 = tbase + 32;  // largest s any t in this chunk attends to
  const int ntiles = (tbase + 33 + 63) >> 6;

  __syncthreads();  // o_l zeroed before any ds_add

#pragma unroll 1
  for (int tile = 0; tile < ntiles; ++tile) {
    const int sb = tile * 64 + wave * 16;  // this wave's s-base
    if (sb > tmax1) break;                 // wave-uniform; no barriers in loop

    // K A-fragment (A[s][k]: s = sb + lrow, k = 4*lgrp + i)
    const int sA = sb + lrow;
    half4 kf;
#pragma unroll
    for (int i = 0; i < 4; ++i) {
      const int k = 4 * lgrp + i;
      const float kv = (k < KK && sA <= TT)
                           ? keyg[((size_t)b * KK + k) * 257 + sA] : 0.f;
      kf[i] = (_Float16)kv;
    }

    // S^T fragments: lane holds t = tbase + tt*16 + lrow, s = sb+4*lgrp+reg
    f32x4 sc0 = __builtin_amdgcn_mfma_f32_16x16x16f16(kf, qf0, zf, 0, 0, 0);
    f32x4 sc1 = __builtin_amdgcn_mfma_f32_16x16x16f16(kf, qf1, zf, 0, 0, 0);

    const int sD = sb + 4 * lgrp;
    half4 pa0, pa1;
#pragma unroll
    for (int r = 0; r < 4; ++r) {
      const int s = sD + r;
      const float e0 = __expf(sc0[r]);
      const float e1 = __expf(sc1[r]);
      const float p0 = (s <= tbase + lrow + 1) ? e0 : 0.f;
      const float p1 = (s <= tbase + 16 + lrow + 1) ? e1 : 0.f;
      su0 += p0;
      su1 += p1;
      pa0[r] = (_Float16)p0;
      pa1[r] = (_Float16)p1;
    }

    // V B-fragments (B[s][h]: h = lrow + 16*ht, s = sD + i) + PV MFMAs
#pragma unroll
    for (int ht = 0; ht < 4; ++ht) {
      const int h = lrow + 16 * ht;
      half4 vf;
#pragma unroll
      for (int i = 0; i < 4; ++i) {
        const int s = sD + i;
        const float cv = (h < HH && s <= TT)
                             ? ctxg[((size_t)b * 257 + s) * HH + h] : 0.f;
        vf[i] = (_Float16)cv;  // mask keeps MFMA operands finite (no 0*inf)
      }
      acc[0][ht] =
          __builtin_amdgcn_mfma_f32_16x16x16f16(pa0, vf, acc[0][ht], 0, 0, 0);
      acc[1][ht] =
          __builtin_amdgcn_mfma_f32_16x16x16f16(pa1, vf, acc[1][ht], 0, 0, 0);
    }
  }

  // combine partial O (D: col h = lrow + 16*ht, row t = 4*lgrp + reg) and su
#pragma unroll
  for (int tt = 0; tt < 2; ++tt)
#pragma unroll
    for (int ht = 0; ht < 4; ++ht)
#pragma unroll
      for (int r = 0; r < 4; ++r) {
        const int tl = tt * 16 + 4 * lgrp + r;
        atomicAdd(&o_l[tl * 66 + lrow + 16 * ht], acc[tt][ht][r]);
      }
  atomicAdd(&o_l[lrow * 66 + 64], su0);
  atomicAdd(&o_l[(16 + lrow) * 66 + 64], su1);
  __syncthreads();

  // epilogue: actions[t][a] = (sum_h O[t][h] W_act[a][h]) / su + b_act[a]
  if (tid < 128) {
    const int tl = tid >> 2;
    const int a = tid & 3;
    const float inv = 1.f / o_l[tl * 66 + 64];
    const float* __restrict__ orow = &o_l[tl * 66];
    const float* __restrict__ wrow = W_act + a * HH;
    float s0 = 0.f, s1 = 0.f;
#pragma unroll
    for (int h = 0; h < HH; h += 2) {
      s0 = fmaf(orow[h], wrow[h], s0);
      if (h + 1 < HH) s1 = fmaf(orow[h + 1], wrow[h + 1], s1);
    }
    out[((size_t)(tbase + tl) * BB + b) * AA + a] =
        fmaf(s0 + s1, inv, b_act[a]);
  }
}

extern "C" void kernel_launch(void* const* d_in, const int* in_sizes, int n_in,
                              void* d_out, int out_size, void* d_ws,
                              size_t ws_size, hipStream_t stream) {
  const float* x = (const float*)d_in[0];
  const float* W_in = (const float*)d_in[1];
  const float* b_in = (const float*)d_in[2];
  const float* W_ctx = (const float*)d_in[3];
  const float* b_ctx = (const float*)d_in[4];
  const float* W_key = (const float*)d_in[5];
  const float* b_key = (const float*)d_in[6];
  const float* W_q = (const float*)d_in[7];
  const float* b_q = (const float*)d_in[8];
  const float* fc = (const float*)d_in[9];
  const float* W_act = (const float*)d_in[10];
  const float* b_act = (const float*)d_in[11];
  float* out = (float*)d_out;
  float* ws = (float*)d_ws;

  float* WT = ws;                                 // 128*52
  float* WHT = ws + 8192;                         // 50*52
  float* WK2T = ws + 12288;                       // 50*64
  float* bias2 = ws + 15616;                      // 64
  float* g = ws + 16384;                          // 131072*52
  float* ctxg = g + (size_t)131072 * GSTRIDE;     // 512*257*50
  float* keyg = ctxg + (size_t)BB * 257 * HH;     // 512*5*257
  float* qg = keyg + (size_t)BB * KK * 257;       // 512*5*256

  hipLaunchKernelGGL(k0_prep, dim3(26), dim3(256), 0, stream, W_in, W_ctx,
                     W_key, W_q, b_key, b_q, WT, WHT, WK2T, bias2);
  hipLaunchKernelGGL(k1_fused, dim3(512), dim3(256), 0, stream, x, WT, WHT,
                     b_in, b_ctx, g);
  hipLaunchKernelGGL(k2_rec, dim3(512), dim3(64), 0, stream, g, WK2T, bias2,
                     fc, ctxg, keyg, qg);
  hipLaunchKernelGGL(k3_attn, dim3(4096), dim3(256), 0, stream, ctxg, keyg, qg,
                     W_act, b_act, out);
}

// Round 9
// 245.074 us; speedup vs baseline: 1.7029x; 1.7029x over previous
//
#include <hip/hip_runtime.h>

#define TT 256
#define BB 512
#define DD 128
#define HH 50
#define KK 5
#define AA 4
#define GSTRIDE 52

#define R50(X) X(0) X(1) X(2) X(3) X(4) X(5) X(6) X(7) X(8) X(9) \
  X(10) X(11) X(12) X(13) X(14) X(15) X(16) X(17) X(18) X(19) \
  X(20) X(21) X(22) X(23) X(24) X(25) X(26) X(27) X(28) X(29) \
  X(30) X(31) X(32) X(33) X(34) X(35) X(36) X(37) X(38) X(39) \
  X(40) X(41) X(42) X(43) X(44) X(45) X(46) X(47) X(48) X(49)

typedef _Float16 half4 __attribute__((ext_vector_type(4)));
typedef float f32x4 __attribute__((ext_vector_type(4)));

// ---------------- K0: weight prep ----------------
__global__ void k0_prep(const float* __restrict__ W_in,
                        const float* __restrict__ W_ctx,
                        const float* __restrict__ W_key,
                        const float* __restrict__ W_q,
                        const float* __restrict__ b_key,
                        const float* __restrict__ b_q,
                        float* __restrict__ WT, float* __restrict__ WHT,
                        float* __restrict__ WK2T, float* __restrict__ bias2) {
  int i = blockIdx.x * 256 + threadIdx.x;
  if (i < DD * 52) {
    int j = i / 52, h = i % 52;
    WT[i] = (h < HH) ? W_in[h * DD + j] : 0.f;
  }
  if (i < HH * 52) {
    int j = i / 52, h = i % 52;
    WHT[i] = (h < HH) ? W_ctx[h * (2 * HH) + HH + j] : 0.f;
  }
  if (i < HH * 64) {
    int j = i >> 6, l = i & 63;
    float v = 0.f;
    if (l < HH) v = W_ctx[l * (2 * HH) + j];
    else if (l < HH + KK) v = W_key[(l - HH) * HH + j];
    else if (l < HH + 2 * KK) v = W_q[(l - HH - KK) * HH + j];
    WK2T[i] = v;
  }
  if (i < 64) {
    float bv = 0.f;
    if (i >= HH && i < HH + KK) bv = b_key[i - HH];
    else if (i >= HH + KK && i < HH + 2 * KK) bv = b_q[i - HH - KK];
    bias2[i] = bv;
  }
}

// ---------------- K1 (fused): g = relu(x@W_in^T+b_in)@Wh^T + b_ctx --------
__global__ __launch_bounds__(256, 2) void k1_fused(
    const float* __restrict__ x, const float* __restrict__ WT,
    const float* __restrict__ WHT, const float* __restrict__ b_in,
    const float* __restrict__ b_ctx, float* __restrict__ g) {
  __shared__ float xs[256 * 17];
  const int tid = threadIdx.x;
  const float* __restrict__ xblk = x + (size_t)blockIdx.x * 256 * DD;

#define DECLA(h) float a##h = b_in[h];
  R50(DECLA)

#pragma unroll 1
  for (int jb = 0; jb < 8; ++jb) {
    __syncthreads();
#pragma unroll
    for (int u = 0; u < 4; ++u) {
      const int f = tid + u * 256;
      const int r = f >> 2, c4 = f & 3;
      const float4 v = *reinterpret_cast<const float4*>(
          xblk + (size_t)r * DD + jb * 16 + c4 * 4);
      float* d = &xs[r * 17 + c4 * 4];
      d[0] = v.x; d[1] = v.y; d[2] = v.z; d[3] = v.w;
    }
    __syncthreads();
    const float* __restrict__ xrow = &xs[tid * 17];
#pragma unroll
    for (int cc = 0; cc < 16; cc += 4) {
      const int j = jb * 16 + cc;
      const float xv0 = xrow[cc + 0];
      const float xv1 = xrow[cc + 1];
      const float xv2 = xrow[cc + 2];
      const float xv3 = xrow[cc + 3];
      const float* __restrict__ w0 = WT + (j + 0) * 52;
      const float* __restrict__ w1 = WT + (j + 1) * 52;
      const float* __restrict__ w2 = WT + (j + 2) * 52;
      const float* __restrict__ w3 = WT + (j + 3) * 52;
#define FMA4(h)                   \
  a##h = fmaf(xv0, w0[h], a##h);  \
  a##h = fmaf(xv1, w1[h], a##h);  \
  a##h = fmaf(xv2, w2[h], a##h);  \
  a##h = fmaf(xv3, w3[h], a##h);
      R50(FMA4)
    }
  }

#define RELUA(h) a##h = fmaxf(a##h, 0.f);
  R50(RELUA)

#define DECLG(h) float g##h = b_ctx[h];
  R50(DECLG)

#define GH(h) g##h = fmaf(av, wh[h], g##h);
#define GJ(j, an) { const float av = an; const float* __restrict__ wh = WHT + (j) * 52; R50(GH) }
  GJ(0, a0) GJ(1, a1) GJ(2, a2) GJ(3, a3) GJ(4, a4)
  GJ(5, a5) GJ(6, a6) GJ(7, a7) GJ(8, a8) GJ(9, a9)
  GJ(10, a10) GJ(11, a11) GJ(12, a12) GJ(13, a13) GJ(14, a14)
  GJ(15, a15) GJ(16, a16) GJ(17, a17) GJ(18, a18) GJ(19, a19)
  GJ(20, a20) GJ(21, a21) GJ(22, a22) GJ(23, a23) GJ(24, a24)
  GJ(25, a25) GJ(26, a26) GJ(27, a27) GJ(28, a28) GJ(29, a29)
  GJ(30, a30) GJ(31, a31) GJ(32, a32) GJ(33, a33) GJ(34, a34)
  GJ(35, a35) GJ(36, a36) GJ(37, a37) GJ(38, a38) GJ(39, a39)
  GJ(40, a40) GJ(41, a41) GJ(42, a42) GJ(43, a43) GJ(44, a44)
  GJ(45, a45) GJ(46, a46) GJ(47, a47) GJ(48, a48) GJ(49, a49)

  const int row = blockIdx.x * 256 + tid;
  float* __restrict__ gr = g + (size_t)row * GSTRIDE;
  *reinterpret_cast<float4*>(gr + 0) = make_float4(g0, g1, g2, g3);
  *reinterpret_cast<float4*>(gr + 4) = make_float4(g4, g5, g6, g7);
  *reinterpret_cast<float4*>(gr + 8) = make_float4(g8, g9, g10, g11);
  *reinterpret_cast<float4*>(gr + 12) = make_float4(g12, g13, g14, g15);
  *reinterpret_cast<float4*>(gr + 16) = make_float4(g16, g17, g18, g19);
  *reinterpret_cast<float4*>(gr + 20) = make_float4(g20, g21, g22, g23);
  *reinterpret_cast<float4*>(gr + 24) = make_float4(g24, g25, g26, g27);
  *reinterpret_cast<float4*>(gr + 28) = make_float4(g28, g29, g30, g31);
  *reinterpret_cast<float4*>(gr + 32) = make_float4(g32, g33, g34, g35);
  *reinterpret_cast<float4*>(gr + 36) = make_float4(g36, g37, g38, g39);
  *reinterpret_cast<float4*>(gr + 40) = make_float4(g40, g41, g42, g43);
  *reinterpret_cast<float4*>(gr + 44) = make_float4(g44, g45, g46, g47);
  *reinterpret_cast<float2*>(gr + 48) = make_float2(g48, g49);
}

// ---------------- K2: per-batch recurrence (512 blocks x 1 wave) -----------
__global__ __launch_bounds__(64, 1) void k2_rec(
    const float* __restrict__ g, const float* __restrict__ WK2T,
    const float* __restrict__ bias2, const float* __restrict__ first_context,
    float* __restrict__ ctxg, float* __restrict__ keyg,
    float* __restrict__ qg) {
  __shared__ __align__(16) float c_lds[64];
  const int b = blockIdx.x;
  const int lane = threadIdx.x;

#define WDECL(j)                            \
  float w##j = WK2T[(j) * 64 + lane];       \
  asm volatile("" : "+v"(w##j));
  R50(WDECL)
  const float bias = bias2[lane];

  const float c0v = (lane < HH) ? first_context[lane] : 0.f;
  c_lds[lane] = c0v;
  if (lane < HH) ctxg[((size_t)b * 257 + 0) * HH + lane] = c0v;

  float gvA = (lane < HH) ? g[((size_t)0 * BB + b) * GSTRIDE + lane] : 0.f;
  float gvB = (lane < HH) ? g[((size_t)1 * BB + b) * GSTRIDE + lane] : 0.f;
  float gvC = (lane < HH) ? g[((size_t)2 * BB + b) * GSTRIDE + lane] : 0.f;

#define DOTQ(j0, j1, j2, j3)                                            \
  {                                                                     \
    const float4 cv = *reinterpret_cast<const float4*>(&c_lds[j0]);     \
    acc0 = fmaf(w##j0, cv.x, acc0);                                     \
    acc1 = fmaf(w##j1, cv.y, acc1);                                     \
    acc2 = fmaf(w##j2, cv.z, acc2);                                     \
    acc3 = fmaf(w##j3, cv.w, acc3);                                     \
  }
#define DOT50L                                                          \
  float acc0 = 0.f, acc1 = 0.f, acc2 = 0.f, acc3 = 0.f;                 \
  DOTQ(0, 1, 2, 3) DOTQ(4, 5, 6, 7) DOTQ(8, 9, 10, 11)                  \
  DOTQ(12, 13, 14, 15) DOTQ(16, 17, 18, 19) DOTQ(20, 21, 22, 23)        \
  DOTQ(24, 25, 26, 27) DOTQ(28, 29, 30, 31) DOTQ(32, 33, 34, 35)        \
  DOTQ(36, 37, 38, 39) DOTQ(40, 41, 42, 43) DOTQ(44, 45, 46, 47)        \
  {                                                                     \
    const float2 cv2 = *reinterpret_cast<const float2*>(&c_lds[48]);    \
    acc0 = fmaf(w48, cv2.x, acc0);                                      \
    acc1 = fmaf(w49, cv2.y, acc1);                                      \
  }                                                                     \
  const float acc = (acc0 + acc1) + (acc2 + acc3);

#pragma unroll 1
  for (int t = 0; t < TT; ++t) {
    float gvn = 0.f;
    if (lane < HH && (t + 3) < TT)
      gvn = g[((size_t)(t + 3) * BB + b) * GSTRIDE + lane];

    DOT50L

    if (lane >= HH && lane < HH + KK)
      keyg[((size_t)b * KK + (lane - HH)) * 257 + t] = acc + bias;
    if (lane >= HH + KK && lane < HH + 2 * KK && t >= 1)
      qg[((size_t)b * KK + (lane - HH - KK)) * 256 + (t - 1)] = acc + bias;

    const float cn = fmaxf(acc + gvA, 0.f);
    gvA = gvB;
    gvB = gvC;
    gvC = gvn;
    if (lane < HH) ctxg[((size_t)b * 257 + (t + 1)) * HH + lane] = cn;
    c_lds[lane] = cn;
  }

  {
    DOT50L
    if (lane >= HH && lane < HH + KK)
      keyg[((size_t)b * KK + (lane - HH)) * 257 + TT] = acc + bias;
    if (lane >= HH + KK && lane < HH + 2 * KK)
      qg[((size_t)b * KK + (lane - HH - KK)) * 256 + (TT - 1)] = acc + bias;
  }
}

// ---------------- K3: MFMA flash attention, LDS-staged ----------------
// Block = (b, 64-t chunk), heavy-first (grid 2048). Each wave owns one 16-t
// tile (tw = tbase + wave*16) and iterates over all s-tiles -> partial O/su
// are wave-private (no atomics). Per s-tile, ct/key tiles are cooperatively
// staged into LDS (coalesced, bulk MLP); K/V fragments read from LDS with
// <=2-way bank aliasing. Swapped QK^T: S^T C-frag (t=lane&15 for mask/su,
// s=4*(lane>>4)+r) feeds PV A-frag in-lane; PV C-frag: t=4*(lane>>4)+r,
// h=(lane&15)+16*ht.
__global__ __launch_bounds__(256, 4) void k3_attn(
    const float* __restrict__ ctxg, const float* __restrict__ keyg,
    const float* __restrict__ qg, const float* __restrict__ W_act,
    const float* __restrict__ b_act, float* __restrict__ out) {
  __shared__ __align__(16) float ct[64 * 66];   // [s_local][h], pad cols
  __shared__ __align__(16) float k_l[8 * 68];   // [k][s_local], rows 5-7 = 0
  __shared__ __align__(16) float o_l[64 * 66];  // [t_local][h]
  __shared__ float su_l[64];

  const int tid = threadIdx.x;
  const int bid = blockIdx.x;
  const int chunk = 3 - (bid >> 9);  // heavy-first
  const int b = bid & 511;
  const int tbase = chunk * 64;
  const int nst = min(tbase + 66, 257);  // ctx rows needed: s in [0, nst)
  const int ntiles = (nst + 63) >> 6;
  const int wave = tid >> 6;
  const int lane = tid & 63;
  const int lrow = lane & 15;
  const int lgrp = lane >> 4;
  const int tw = tbase + wave * 16;  // this wave's t-tile base

  if (tid < 3 * 68) k_l[5 * 68 + tid] = 0.f;  // zero K pad rows once

  // Q B-fragment: B[k][t], t = tw + lrow, k = 4*lgrp + i
  half4 qf;
#pragma unroll
  for (int i = 0; i < 4; ++i) {
    const int k = 4 * lgrp + i;
    qf[i] = (_Float16)((k < KK) ? qg[((size_t)b * KK + k) * 256 + tw + lrow]
                                : 0.f);
  }

  const f32x4 zf = {0.f, 0.f, 0.f, 0.f};
  f32x4 acc0 = zf, acc1 = zf, acc2 = zf, acc3 = zf;
  float su = 0.f;

#pragma unroll 1
  for (int tile = 0; tile < ntiles; ++tile) {
    __syncthreads();  // previous tile fully consumed (also covers k_l zero)
    {                 // stage ct rows [tile*64, +64) -> ct[sl][h], stride 66
      const int r = tid >> 2;
      const int c0 = (tid & 3) * 16;
      const int srow = tile * 64 + r;
      const float* src = ctxg + ((size_t)b * 257 + srow) * HH;
      const bool sv = (srow < nst);
#pragma unroll
      for (int u = 0; u < 8; ++u) {
        const int c = c0 + u * 2;
        float2 v = make_float2(0.f, 0.f);
        if (sv && c < HH) v = *reinterpret_cast<const float2*>(src + c);
        *reinterpret_cast<float2*>(&ct[r * 66 + c]) = v;
      }
    }
    {  // stage keys k_l[k][sl]
      for (int i = tid; i < KK * 64; i += 256) {
        const int k = i >> 6, sl = i & 63;
        const int s = tile * 64 + sl;
        k_l[k * 68 + sl] =
            (s <= TT) ? keyg[((size_t)b * KK + k) * 257 + s] : 0.f;
      }
    }
    __syncthreads();

    if (tile * 64 <= tw + 16) {  // wave-uniform
#pragma unroll 1
      for (int su16 = 0; su16 < 4; ++su16) {
        const int sb = tile * 64 + su16 * 16;
        if (sb > tw + 16) break;  // wave-uniform

        // K A-fragment: A[s][k], s = sb + lrow, k = 4*lgrp + i (rows>=5 = 0)
        half4 kf;
#pragma unroll
        for (int i = 0; i < 4; ++i)
          kf[i] = (_Float16)k_l[(4 * lgrp + i) * 68 + su16 * 16 + lrow];

        // S^T: lane holds t = tw + lrow, s = sb + 4*lgrp + r
        const f32x4 sc =
            __builtin_amdgcn_mfma_f32_16x16x16f16(kf, qf, zf, 0, 0, 0);

        half4 pa;
#pragma unroll
        for (int r = 0; r < 4; ++r) {
          const int s = sb + 4 * lgrp + r;
          const float p = (s <= tw + lrow + 1) ? __expf(sc[r]) : 0.f;
          su += p;
          pa[r] = (_Float16)p;
        }

        // PV: vf B-frag B[s][h], s = sb + 4*lgrp + i, h = lrow + 16*ht
        const int vbase = su16 * 16 + 4 * lgrp;
#define PVHT(HT, ACC)                                                     \
  {                                                                       \
    half4 vf;                                                             \
    vf[0] = (_Float16)ct[(vbase + 0) * 66 + lrow + 16 * HT];              \
    vf[1] = (_Float16)ct[(vbase + 1) * 66 + lrow + 16 * HT];              \
    vf[2] = (_Float16)ct[(vbase + 2) * 66 + lrow + 16 * HT];              \
    vf[3] = (_Float16)ct[(vbase + 3) * 66 + lrow + 16 * HT];              \
    ACC = __builtin_amdgcn_mfma_f32_16x16x16f16(pa, vf, ACC, 0, 0, 0);    \
  }
        PVHT(0, acc0) PVHT(1, acc1) PVHT(2, acc2) PVHT(3, acc3)
      }
    }
  }

  // su: reduce over lgrp (4 lanes hold partials for t = tw + lrow)
  su += __shfl_xor(su, 16, 64);
  su += __shfl_xor(su, 32, 64);
  if (lane < 16) su_l[wave * 16 + lane] = su;

  // O: PV C-frag -> o_l[t_local][h], t_local = wave*16 + 4*lgrp + r
#pragma unroll
  for (int r = 0; r < 4; ++r) {
    const int trow = wave * 16 + 4 * lgrp + r;
    o_l[trow * 66 + lrow + 0] = acc0[r];
    o_l[trow * 66 + lrow + 16] = acc1[r];
    o_l[trow * 66 + lrow + 32] = acc2[r];
    o_l[trow * 66 + lrow + 48] = acc3[r];
  }
  __syncthreads();

  // epilogue: out[t][a] = (sum_h O[t][h] W_act[a][h]) / su + b_act[a]
  {
    const int tl = tid >> 2;  // 0..63
    const int a = tid & 3;
    const float inv = 1.f / su_l[tl];
    const float* orow = &o_l[tl * 66];
    const float* wrow = W_act + a * HH;
    float s0 = 0.f, s1 = 0.f;
#pragma unroll
    for (int h = 0; h < HH; h += 2) {
      s0 = fmaf(orow[h], wrow[h], s0);
      s1 = fmaf(orow[h + 1], wrow[h + 1], s1);
    }
    out[((size_t)(tbase + tl) * BB + b) * AA + a] =
        fmaf(s0 + s1, inv, b_act[a]);
  }
}

extern "C" void kernel_launch(void* const* d_in, const int* in_sizes, int n_in,
                              void* d_out, int out_size, void* d_ws,
                              size_t ws_size, hipStream_t stream) {
  const float* x = (const float*)d_in[0];
  const float* W_in = (const float*)d_in[1];
  const float* b_in = (const float*)d_in[2];
  const float* W_ctx = (const float*)d_in[3];
  const float* b_ctx = (const float*)d_in[4];
  const float* W_key = (const float*)d_in[5];
  const float* b_key = (const float*)d_in[6];
  const float* W_q = (const float*)d_in[7];
  const float* b_q = (const float*)d_in[8];
  const float* fc = (const float*)d_in[9];
  const float* W_act = (const float*)d_in[10];
  const float* b_act = (const float*)d_in[11];
  float* out = (float*)d_out;
  float* ws = (float*)d_ws;

  float* WT = ws;                                 // 128*52
  float* WHT = ws + 8192;                         // 50*52
  float* WK2T = ws + 12288;                       // 50*64
  float* bias2 = ws + 15616;                      // 64
  float* g = ws + 16384;                          // 131072*52
  float* ctxg = g + (size_t)131072 * GSTRIDE;     // 512*257*50
  float* keyg = ctxg + (size_t)BB * 257 * HH;     // 512*5*257
  float* qg = keyg + (size_t)BB * KK * 257;       // 512*5*256

  hipLaunchKernelGGL(k0_prep, dim3(26), dim3(256), 0, stream, W_in, W_ctx,
                     W_key, W_q, b_key, b_q, WT, WHT, WK2T, bias2);
  hipLaunchKernelGGL(k1_fused, dim3(512), dim3(256), 0, stream, x, WT, WHT,
                     b_in, b_ctx, g);
  hipLaunchKernelGGL(k2_rec, dim3(512), dim3(64), 0, stream, g, WK2T, bias2,
                     fc, ctxg, keyg, qg);
  hipLaunchKernelGGL(k3_attn, dim3(2048), dim3(256), 0, stream, ctxg, keyg, qg,
                     W_act, b_act, out);
}